// Round 17
// baseline (41.816 us; speedup 1.0000x reference)
//
#include <hip/hip_runtime.h>
#include <hip/hip_fp16.h>
#include <math.h>

constexpr int B    = 512;
constexpr int NIN  = 1024;
constexpr int NK   = 128;
constexpr int DK   = 5;
constexpr int NF   = NK * DK;     // 640 flattened kernel columns
constexpr int NOUT = NIN + NK;    // 1152
constexpr int SPLITK = 8;         // K chunks (128 each)
constexpr int LDA = 136;          // LDS row stride in halves (128 + 8 pad)
#define LOG2E 1.44269504088896f

typedef _Float16 f16x2v __attribute__((ext_vector_type(2)));
typedef _Float16 f16x4 __attribute__((ext_vector_type(4)));
typedef _Float16 f16x8 __attribute__((ext_vector_type(8)));
typedef float    f32x4 __attribute__((ext_vector_type(4)));

// ---------------------------------------------------------------------------
// Kernel 1: split-K MFMA GEMM (R10 structure) + f-region bias pre-init.
//   grid 1280; blocks 0..255 additionally write out[b][NIN+k] = bias[k]
//   (pairwise then atomicAdds row/col partials on top).
// ---------------------------------------------------------------------------
__global__ __launch_bounds__(256) void gemm_kernel(
        const float* __restrict__ x,       // [512][1024]
        const float* __restrict__ theta,   // [1024][640]
        const float* __restrict__ bias,    // [128]
        __half* __restrict__ actvP16,      // [8][640][512]
        float* __restrict__ ps,            // [8][640]
        float* __restrict__ out) {         // [512][1152]
    __shared__ _Float16 Ath[32 * LDA];
    __shared__ _Float16 Bxh[64 * LDA];
    __shared__ float    red2[32][33];

    const int t    = threadIdx.x;
    const int tile = blockIdx.x >> 3;
    const int z    = blockIdx.x & 7;
    const int nt   = tile >> 3;
    const int bt   = tile & 7;
    const int n0   = nt * 32;
    const int b0   = bt * 64;
    const bool do_ps = (bt == 0);
    const int kw   = z * 128;

    // f-region init: 256 blocks x 256 thr = 512 rows x 128 cols
    if (blockIdx.x < 256) {
        const int u   = blockIdx.x * 256 + t;
        const int row = u >> 7;
        const int col = u & 127;
        out[(size_t)row * NOUT + NIN + col] = bias[col];
    }

    const int kq = t >> 3;
    const int nc = (t & 7) * 4;
    float4 tv0 = *(const float4*)&theta[(kw + kq*4 + 0) * NF + n0 + nc];
    float4 tv1 = *(const float4*)&theta[(kw + kq*4 + 1) * NF + n0 + nc];
    float4 tv2 = *(const float4*)&theta[(kw + kq*4 + 2) * NF + n0 + nc];
    float4 tv3 = *(const float4*)&theta[(kw + kq*4 + 3) * NF + n0 + nc];

    const int br = t >> 2;
    const int ki = t & 3;
    float4 xv[8];
    #pragma unroll
    for (int i = 0; i < 8; ++i)
        xv[i] = *(const float4*)&x[(b0 + br) * NIN + kw + (ki + i * 4) * 4];

    if (do_ps) {
        red2[kq][nc + 0] = tv0.x*tv0.x + tv1.x*tv1.x + tv2.x*tv2.x + tv3.x*tv3.x;
        red2[kq][nc + 1] = tv0.y*tv0.y + tv1.y*tv1.y + tv2.y*tv2.y + tv3.y*tv3.y;
        red2[kq][nc + 2] = tv0.z*tv0.z + tv1.z*tv1.z + tv2.z*tv2.z + tv3.z*tv3.z;
        red2[kq][nc + 3] = tv0.w*tv0.w + tv1.w*tv1.w + tv2.w*tv2.w + tv3.w*tv3.w;
    }

    {
        f16x4 h;
        h[0]=(_Float16)tv0.x; h[1]=(_Float16)tv1.x; h[2]=(_Float16)tv2.x; h[3]=(_Float16)tv3.x;
        *(f16x4*)&Ath[(nc + 0) * LDA + kq * 4] = h;
        h[0]=(_Float16)tv0.y; h[1]=(_Float16)tv1.y; h[2]=(_Float16)tv2.y; h[3]=(_Float16)tv3.y;
        *(f16x4*)&Ath[(nc + 1) * LDA + kq * 4] = h;
        h[0]=(_Float16)tv0.z; h[1]=(_Float16)tv1.z; h[2]=(_Float16)tv2.z; h[3]=(_Float16)tv3.z;
        *(f16x4*)&Ath[(nc + 2) * LDA + kq * 4] = h;
        h[0]=(_Float16)tv0.w; h[1]=(_Float16)tv1.w; h[2]=(_Float16)tv2.w; h[3]=(_Float16)tv3.w;
        *(f16x4*)&Ath[(nc + 3) * LDA + kq * 4] = h;
    }
    #pragma unroll
    for (int i = 0; i < 8; ++i) {
        f16x4 h;
        h[0] = (_Float16)xv[i].x;  h[1] = (_Float16)xv[i].y;
        h[2] = (_Float16)xv[i].z;  h[3] = (_Float16)xv[i].w;
        *(f16x4*)&Bxh[br * LDA + (ki + i * 4) * 4] = h;
    }
    __syncthreads();

    const int w   = t >> 6;
    const int l   = t & 63;
    const int r16 = l & 15;
    const int kg  = l >> 4;

    f32x4 acc0 = {0.f,0.f,0.f,0.f}, acc1 = {0.f,0.f,0.f,0.f};
    #pragma unroll
    for (int ks = 0; ks < 4; ++ks) {
        const f16x8 bv  = *(const f16x8*)&Bxh[(w*16 + r16)*LDA + ks*32 + kg*8];
        const f16x8 av0 = *(const f16x8*)&Ath[( 0 + r16)*LDA + ks*32 + kg*8];
        const f16x8 av1 = *(const f16x8*)&Ath[(16 + r16)*LDA + ks*32 + kg*8];
        acc0 = __builtin_amdgcn_mfma_f32_16x16x32_f16(av0, bv, acc0, 0, 0, 0);
        acc1 = __builtin_amdgcn_mfma_f32_16x16x32_f16(av1, bv, acc1, 0, 0, 0);
    }

    {
        __half* dst = actvP16 + (size_t)z * NF * B
                    + (size_t)(n0 + kg*4) * B + b0 + w*16 + r16;
        #pragma unroll
        for (int j = 0; j < 4; ++j) {
            dst[j*B]          = __float2half(acc0[j]);
            dst[(16 + j) * B] = __float2half(acc1[j]);
        }
    }
    if (do_ps) {
        __syncthreads();
        if (t < 32) {
            float tot = 0.f;
            #pragma unroll
            for (int rr = 0; rr < 32; ++rr) tot += red2[rr][t];
            ps[z * NF + n0 + t] = tot;
        }
    }
}

// ---------------------------------------------------------------------------
// Kernel 2: pairwise — SYMMETRIC (each unordered pair computed once).
// grid (128 k, 2 h) x 1024 thr.  Wave W = h*16+w owns col-groups {W, 63-W}
// (8 cols each; 9 row-strips per wave total — balanced).  Strict upper
// triangle r < c; pair adds to rowsum[r] (lane acc -> LDS atomic) and
// colsum[c] (lane half2 acc -> f32 butterfly -> LDS atomic).  Final:
// atomicAdd(out[b][NIN+k], rowsum[b]+colsum[b]) on top of gemm's bias init.
// ---------------------------------------------------------------------------
__global__ __launch_bounds__(1024, 4) void pairwise_kernel(
        const __half* __restrict__ actvP16,// [8][640][512]
        const float* __restrict__ ps,      // [8][640]
        const float* __restrict__ lws,     // [640]
        const float* __restrict__ x,       // [512][1024]
        float* __restrict__ out) {         // [512][1152]
    __shared__ __half a16s[DK * B];        // 5120 B
    __shared__ float  rowsum[B];
    __shared__ float  colsum[B];
    __shared__ float  s_sh[DK];
    __shared__ float  red_ps[DK * SPLITK];

    const int k = blockIdx.x;
    const int h = blockIdx.y;              // col-group half (0..1)
    const int t = threadIdx.x;

    // zero accumulators + x passthrough (rows k*4 + 2h, +1)
    if (t < 512) {
        rowsum[t] = 0.f;
    } else {
        colsum[t - 512] = 0.f;
        const int u = t - 512;             // 0..511 = 2 rows x 256 float4
        const int row = k * 4 + 2 * h + (u >> 8);
        const int c4  = u & 255;
        ((float4*)out)[row * (NOUT/4) + c4] = ((const float4*)x)[row * (NIN/4) + c4];
    }
    if (t >= 320 && t < 320 + DK * SPLITK) {
        const int u = t - 320;
        red_ps[u] = ps[(u / DK) * NF + k * DK + (u % DK)];
    }

    // ---- split-K reduce + scale into a16s (same as R16) ----
    const size_t slab = (size_t)k * DK * B;
    float accf[8];
    #pragma unroll
    for (int i = 0; i < 8; ++i) accf[i] = 0.f;
    if (t < 320) {
        #pragma unroll
        for (int z = 0; z < SPLITK; ++z) {
            const f16x8 v = *(const f16x8*)(actvP16 + (size_t)z * NF * B + slab + t * 8);
            #pragma unroll
            for (int i = 0; i < 8; ++i) accf[i] += (float)v[i];
        }
    }
    __syncthreads();
    if (t < DK) {
        float sum = 0.f;
        #pragma unroll
        for (int c = 0; c < SPLITK; ++c) sum += red_ps[c * DK + t];
        s_sh[t] = __expf(lws[k * DK + t]) * rsqrtf(sum) * LOG2E;
    }
    __syncthreads();
    if (t < 320) {
        const float s = s_sh[t >> 6];
        f16x8 hv;
        #pragma unroll
        for (int i = 0; i < 8; ++i) hv[i] = (_Float16)(accf[i] * s);
        *(f16x8*)&a16s[t * 8] = hv;
    }
    __syncthreads();

    // ---- symmetric sweep ----
    const int w = t >> 6;                  // wave 0..15
    const int l = t & 63;
    const int W = h * 16 + w;              // 0..31

    union W8 { f16x8 v; __half2 h2[4]; };
    union HU { __half2 h; unsigned u; };

    #pragma unroll
    for (int jj = 0; jj < 2; ++jj) {
        const int j  = jj ? (63 - W) : W;  // col-group 0..63
        const int c0 = j * 8;
        W8 cd[5];
        #pragma unroll
        for (int d = 0; d < DK; ++d)
            cd[d].v = *(const f16x8*)&a16s[d * B + c0];   // wave-uniform b128

        HU ca[4];
        ca[0].u = 0u; ca[1].u = 0u; ca[2].u = 0u; ca[3].u = 0u;

        const int mstrip = j >> 3;
        const int q = l - 8 * (j & 7);     // diag: include col p iff p > q
        for (int i = 0; i <= mstrip; ++i) {
            const int r = i * 64 + l;
            __half2 A2[DK];
            #pragma unroll
            for (int d = 0; d < DK; ++d)
                A2[d] = __half2half2(a16s[d * B + r]);
            const bool diag = (i == mstrip);
            float rowacc = 0.f;
            #pragma unroll
            for (int s = 0; s < 4; ++s) {
                __half2 dA = __habs2(__hsub2(A2[0], cd[0].h2[s]));
                dA = __hadd2(dA, __habs2(__hsub2(A2[1], cd[1].h2[s])));
                dA = __hadd2(dA, __habs2(__hsub2(A2[2], cd[2].h2[s])));
                dA = __hadd2(dA, __habs2(__hsub2(A2[3], cd[3].h2[s])));
                dA = __hadd2(dA, __habs2(__hsub2(A2[4], cd[4].h2[s])));
                HU e; e.h = h2exp2(__hneg2(dA));
                if (diag) {
                    HU m;
                    m.u = ((2*s     > q) ? 0x00003C00u : 0u)
                        | ((2*s + 1 > q) ? 0x3C000000u : 0u);
                    e.h = __hmul2(e.h, m.h);
                }
#if __has_builtin(__builtin_amdgcn_fdot2)
                {
                    HU ones; ones.u = 0x3C003C00u;
                    rowacc = __builtin_amdgcn_fdot2(
                        *(f16x2v*)&e.u, *(f16x2v*)&ones.u, rowacc, false);
                }
#else
                rowacc += __low2float(e.h) + __high2float(e.h);
#endif
                ca[s].h = __hadd2(ca[s].h, e.h);   // <=9 terms in f16
            }
            atomicAdd(&rowsum[r], rowacc);
        }

        // f32 butterfly col reduce (8 cols)
        float c0f = __low2float(ca[0].h), c1f = __high2float(ca[0].h);
        float c2f = __low2float(ca[1].h), c3f = __high2float(ca[1].h);
        float c4f = __low2float(ca[2].h), c5f = __high2float(ca[2].h);
        float c6f = __low2float(ca[3].h), c7f = __high2float(ca[3].h);
        #pragma unroll
        for (int msk = 1; msk < 64; msk <<= 1) {
            c0f += __shfl_xor(c0f, msk, 64);
            c1f += __shfl_xor(c1f, msk, 64);
            c2f += __shfl_xor(c2f, msk, 64);
            c3f += __shfl_xor(c3f, msk, 64);
            c4f += __shfl_xor(c4f, msk, 64);
            c5f += __shfl_xor(c5f, msk, 64);
            c6f += __shfl_xor(c6f, msk, 64);
            c7f += __shfl_xor(c7f, msk, 64);
        }
        if (l < 8) {
            const float v = (l == 0) ? c0f : (l == 1) ? c1f : (l == 2) ? c2f :
                            (l == 3) ? c3f : (l == 4) ? c4f : (l == 5) ? c5f :
                            (l == 6) ? c6f : c7f;
            atomicAdd(&colsum[c0 + l], v);
        }
    }
    __syncthreads();

    if (t < 512)
        atomicAdd(&out[(size_t)t * NOUT + NIN + k], rowsum[t] + colsum[t]);
}

// ---------------------------------------------------------------------------
extern "C" void kernel_launch(void* const* d_in, const int* in_sizes, int n_in,
                              void* d_out, int out_size, void* d_ws, size_t ws_size,
                              hipStream_t stream) {
    const float* x     = (const float*)d_in[0];   // [512,1024]
    const float* theta = (const float*)d_in[1];   // [1024,128,5]
    const float* lws   = (const float*)d_in[2];   // [128,5]
    const float* bias  = (const float*)d_in[3];   // [128]
    float* out = (float*)d_out;                   // [512,1152]

    // ws layout: ps @0 (64KB pad), actvP16 f16 8 slabs @64KB (5.24MB)
    char* wsb = (char*)d_ws;
    float*  ps       = (float*)wsb;
    __half* actvP16  = (__half*)(wsb + (64 << 10));

    gemm_kernel<<<dim3(1280), 256, 0, stream>>>(x, theta, bias, actvP16, ps, out);
    pairwise_kernel<<<dim3(NK, 2), 1024, 0, stream>>>(actvP16, ps, lws, x, out);
}

// Round 18
// 23.994 us; speedup vs baseline: 1.7428x; 1.7428x over previous
//
#include <hip/hip_runtime.h>
#include <hip/hip_fp16.h>
#include <math.h>

constexpr int B    = 512;
constexpr int NIN  = 1024;
constexpr int NK   = 128;
constexpr int DK   = 5;
constexpr int NF   = NK * DK;     // 640 flattened kernel columns
constexpr int NOUT = NIN + NK;    // 1152
constexpr int SPLITK = 8;         // K chunks (128 each)
constexpr int LDA = 136;          // LDS row stride in halves (128 + 8 pad)
#define LOG2E 1.44269504088896f
// Schraudolph exp2: exp2(x) ~= int_as_float((int)(2^23*x + BIAS)), minimax bias
#define EXP2_BIAS 1064986816.0f   // (127<<23) - 366400 (delta = 0.0437)
#define EXP2_S0   0.9781963f      // approx value at x = 0 (diagonal term)

typedef _Float16 f16x4 __attribute__((ext_vector_type(4)));
typedef _Float16 f16x8 __attribute__((ext_vector_type(8)));
typedef float    f32x4 __attribute__((ext_vector_type(4)));

// ---------------------------------------------------------------------------
// Kernel 1: split-K MFMA GEMM — byte-identical to R10 (gemm+gap ≈ 4.9 µs).
// ---------------------------------------------------------------------------
__global__ __launch_bounds__(256) void gemm_kernel(
        const float* __restrict__ x,       // [512][1024]
        const float* __restrict__ theta,   // [1024][640]
        __half* __restrict__ actvP16,      // [8][640][512]
        float* __restrict__ ps) {          // [8][640]
    __shared__ _Float16 Ath[32 * LDA];
    __shared__ _Float16 Bxh[64 * LDA];
    __shared__ float    red2[32][33];

    const int t    = threadIdx.x;
    const int tile = blockIdx.x >> 3;
    const int z    = blockIdx.x & 7;
    const int nt   = tile >> 3;
    const int bt   = tile & 7;
    const int n0   = nt * 32;
    const int b0   = bt * 64;
    const bool do_ps = (bt == 0);
    const int kw   = z * 128;

    const int kq = t >> 3;
    const int nc = (t & 7) * 4;
    float4 tv0 = *(const float4*)&theta[(kw + kq*4 + 0) * NF + n0 + nc];
    float4 tv1 = *(const float4*)&theta[(kw + kq*4 + 1) * NF + n0 + nc];
    float4 tv2 = *(const float4*)&theta[(kw + kq*4 + 2) * NF + n0 + nc];
    float4 tv3 = *(const float4*)&theta[(kw + kq*4 + 3) * NF + n0 + nc];

    const int br = t >> 2;
    const int ki = t & 3;
    float4 xv[8];
    #pragma unroll
    for (int i = 0; i < 8; ++i)
        xv[i] = *(const float4*)&x[(b0 + br) * NIN + kw + (ki + i * 4) * 4];

    if (do_ps) {
        red2[kq][nc + 0] = tv0.x*tv0.x + tv1.x*tv1.x + tv2.x*tv2.x + tv3.x*tv3.x;
        red2[kq][nc + 1] = tv0.y*tv0.y + tv1.y*tv1.y + tv2.y*tv2.y + tv3.y*tv3.y;
        red2[kq][nc + 2] = tv0.z*tv0.z + tv1.z*tv1.z + tv2.z*tv2.z + tv3.z*tv3.z;
        red2[kq][nc + 3] = tv0.w*tv0.w + tv1.w*tv1.w + tv2.w*tv2.w + tv3.w*tv3.w;
    }

    {
        f16x4 h;
        h[0]=(_Float16)tv0.x; h[1]=(_Float16)tv1.x; h[2]=(_Float16)tv2.x; h[3]=(_Float16)tv3.x;
        *(f16x4*)&Ath[(nc + 0) * LDA + kq * 4] = h;
        h[0]=(_Float16)tv0.y; h[1]=(_Float16)tv1.y; h[2]=(_Float16)tv2.y; h[3]=(_Float16)tv3.y;
        *(f16x4*)&Ath[(nc + 1) * LDA + kq * 4] = h;
        h[0]=(_Float16)tv0.z; h[1]=(_Float16)tv1.z; h[2]=(_Float16)tv2.z; h[3]=(_Float16)tv3.z;
        *(f16x4*)&Ath[(nc + 2) * LDA + kq * 4] = h;
        h[0]=(_Float16)tv0.w; h[1]=(_Float16)tv1.w; h[2]=(_Float16)tv2.w; h[3]=(_Float16)tv3.w;
        *(f16x4*)&Ath[(nc + 3) * LDA + kq * 4] = h;
    }
    #pragma unroll
    for (int i = 0; i < 8; ++i) {
        f16x4 h;
        h[0] = (_Float16)xv[i].x;  h[1] = (_Float16)xv[i].y;
        h[2] = (_Float16)xv[i].z;  h[3] = (_Float16)xv[i].w;
        *(f16x4*)&Bxh[br * LDA + (ki + i * 4) * 4] = h;
    }
    __syncthreads();

    const int w   = t >> 6;
    const int l   = t & 63;
    const int r16 = l & 15;
    const int kg  = l >> 4;

    f32x4 acc0 = {0.f,0.f,0.f,0.f}, acc1 = {0.f,0.f,0.f,0.f};
    #pragma unroll
    for (int ks = 0; ks < 4; ++ks) {
        const f16x8 bv  = *(const f16x8*)&Bxh[(w*16 + r16)*LDA + ks*32 + kg*8];
        const f16x8 av0 = *(const f16x8*)&Ath[( 0 + r16)*LDA + ks*32 + kg*8];
        const f16x8 av1 = *(const f16x8*)&Ath[(16 + r16)*LDA + ks*32 + kg*8];
        acc0 = __builtin_amdgcn_mfma_f32_16x16x32_f16(av0, bv, acc0, 0, 0, 0);
        acc1 = __builtin_amdgcn_mfma_f32_16x16x32_f16(av1, bv, acc1, 0, 0, 0);
    }

    {
        __half* dst = actvP16 + (size_t)z * NF * B
                    + (size_t)(n0 + kg*4) * B + b0 + w*16 + r16;
        #pragma unroll
        for (int j = 0; j < 4; ++j) {
            dst[j*B]          = __float2half(acc0[j]);
            dst[(16 + j) * B] = __float2half(acc1[j]);
        }
    }
    if (do_ps) {
        __syncthreads();
        if (t < 32) {
            float tot = 0.f;
            #pragma unroll
            for (int rr = 0; rr < 32; ++rr) tot += red2[rr][t];
            ps[z * NF + n0 + t] = tot;
        }
    }
}

// ---------------------------------------------------------------------------
// Kernel 2: pairwise — R10 structure; exp via Schraudolph bit-trick (no trans).
// grid (128 k, 4 e) x 512 thr (2 blocks/CU, 16 waves/CU).
// ---------------------------------------------------------------------------
__global__ __launch_bounds__(512) void pairwise_kernel(
        const __half* __restrict__ actvP16,// [8][640][512]
        const float* __restrict__ ps,      // [8][640]
        const float* __restrict__ lws,     // [640]
        const float* __restrict__ bias,    // [128]
        const float* __restrict__ x,       // [512][1024]
        float* __restrict__ out) {         // [512][1152]
    __shared__ __half a16s[DK * B];        // 5120 B
    __shared__ float  red[8 * 128];
    __shared__ float  s_sh[DK];
    __shared__ float  red_ps[DK * SPLITK];

    const int k = blockIdx.x;
    const int e = blockIdx.y;              // b-quarter (0..3)
    const int t = threadIdx.x;

    if (t >= 256) {
        const int u = t - 256;
        const int row = k * 4 + e;
        ((float4*)out)[row * (NOUT/4) + u] = ((const float4*)x)[row * (NIN/4) + u];
    }
    if (t >= 448 && t < 448 + DK * SPLITK) {
        const int u = t - 448;
        red_ps[u] = ps[(u / DK) * NF + k * DK + (u % DK)];
    }

    // ---- split-K reduce into f32 regs: unit t = 8 halves (t < 320) ----
    const size_t slab = (size_t)k * DK * B;
    float accf[8];
    #pragma unroll
    for (int i = 0; i < 8; ++i) accf[i] = 0.f;
    if (t < 320) {
        #pragma unroll
        for (int z = 0; z < SPLITK; ++z) {
            const f16x8 v = *(const f16x8*)(actvP16 + (size_t)z * NF * B + slab + t * 8);
            #pragma unroll
            for (int i = 0; i < 8; ++i) accf[i] += (float)v[i];
        }
    }
    __syncthreads();
    if (t < DK) {
        float sum = 0.f;
        #pragma unroll
        for (int c = 0; c < SPLITK; ++c) sum += red_ps[c * DK + t];
        s_sh[t] = __expf(lws[k * DK + t]) * rsqrtf(sum) * LOG2E;
    }
    __syncthreads();
    if (t < 320) {
        const float s = s_sh[t >> 6];      // d = t/64, wave-uniform
        f16x8 h;
        #pragma unroll
        for (int i = 0; i < 8; ++i) h[i] = (_Float16)(accf[i] * s);
        *(f16x8*)&a16s[t * 8] = h;
    }
    __syncthreads();

    const int g  = t >> 6;                 // wave-uniform b' eighth (0..7)
    const int r  = t & 63;
    const int ba = e * 128 + r;
    const int bb = ba + 64;

    __half2 A2[DK], B2[DK];
    #pragma unroll
    for (int d = 0; d < DK; ++d) {
        A2[d] = __half2half2(a16s[d * B + ba]);
        B2[d] = __half2half2(a16s[d * B + bb]);
    }

    float accA = 0.f, accB = 0.f;
    const int bp0 = g * 64;

    union W8 { f16x8 v; __half2 h[4]; };

    #pragma unroll 2
    for (int m = 0; m < 8; ++m) {
        const int bp = bp0 + m * 8;        // wave-uniform -> LDS b128 broadcast
        W8 w0, w1, w2, w3, w4;
        w0.v = *(const f16x8*)&a16s[0*B + bp];
        w1.v = *(const f16x8*)&a16s[1*B + bp];
        w2.v = *(const f16x8*)&a16s[2*B + bp];
        w3.v = *(const f16x8*)&a16s[3*B + bp];
        w4.v = *(const f16x8*)&a16s[4*B + bp];
        #pragma unroll
        for (int c = 0; c < 4; ++c) {
            __half2 dA = __habs2(__hsub2(A2[0], w0.h[c]));
            dA = __hadd2(dA, __habs2(__hsub2(A2[1], w1.h[c])));
            dA = __hadd2(dA, __habs2(__hsub2(A2[2], w2.h[c])));
            dA = __hadd2(dA, __habs2(__hsub2(A2[3], w3.h[c])));
            dA = __hadd2(dA, __habs2(__hsub2(A2[4], w4.h[c])));
            __half2 dB = __habs2(__hsub2(B2[0], w0.h[c]));
            dB = __hadd2(dB, __habs2(__hsub2(B2[1], w1.h[c])));
            dB = __hadd2(dB, __habs2(__hsub2(B2[2], w2.h[c])));
            dB = __hadd2(dB, __habs2(__hsub2(B2[3], w3.h[c])));
            dB = __hadd2(dB, __habs2(__hsub2(B2[4], w4.h[c])));
            // Schraudolph exp2(-d): 1 fma + 1 cvt + reinterpret per exp
            const float dAlo = __low2float(dA), dAhi = __high2float(dA);
            const float dBlo = __low2float(dB), dBhi = __high2float(dB);
            accA += __int_as_float((int)fmaf(dAlo, -8388608.0f, EXP2_BIAS));
            accA += __int_as_float((int)fmaf(dAhi, -8388608.0f, EXP2_BIAS));
            accB += __int_as_float((int)fmaf(dBlo, -8388608.0f, EXP2_BIAS));
            accB += __int_as_float((int)fmaf(dBhi, -8388608.0f, EXP2_BIAS));
        }
    }
    red[g * 128 + r]      = accA;
    red[g * 128 + 64 + r] = accB;
    __syncthreads();
    if (t < 128) {
        float f = -EXP2_S0 + bias[k];      // subtract approx(0) = diagonal term
        #pragma unroll
        for (int gg = 0; gg < 8; ++gg) f += red[gg * 128 + t];
        out[(e * 128 + t) * NOUT + NIN + k] = f;
    }
}

// ---------------------------------------------------------------------------
extern "C" void kernel_launch(void* const* d_in, const int* in_sizes, int n_in,
                              void* d_out, int out_size, void* d_ws, size_t ws_size,
                              hipStream_t stream) {
    const float* x     = (const float*)d_in[0];   // [512,1024]
    const float* theta = (const float*)d_in[1];   // [1024,128,5]
    const float* lws   = (const float*)d_in[2];   // [128,5]
    const float* bias  = (const float*)d_in[3];   // [128]
    float* out = (float*)d_out;                   // [512,1152]

    // ws layout: ps @0 (64KB pad), actvP16 f16 8 slabs @64KB (5.24MB)
    char* wsb = (char*)d_ws;
    float*  ps       = (float*)wsb;
    __half* actvP16  = (__half*)(wsb + (64 << 10));

    gemm_kernel<<<dim3(1280), 256, 0, stream>>>(x, theta, actvP16, ps);
    pairwise_kernel<<<dim3(NK, 4), 512, 0, stream>>>(actvP16, ps, lws, bias, x, out);
}